// Round 8
// baseline (7430.824 us; speedup 1.0000x reference)
//
#include <hip/hip_runtime.h>
#include <stdint.h>

// LoraLSTM on MI355X. FP32 I/O, bf16 internal pipeline.
// R8: rec critical-path overhaul —
//  - gx packed per-thread: GEMM writes [dir][wg][lcol][tid][16] so rec reads 2xb128
//    per thread per step (dense lines; kills the 2x FETCH overshoot of row-major gx)
//  - per-wave flags (64/dir, 16B stride), RELEASE store (vmcnt drain), all-wave
//    relaxed polling (one 64-lane load = all flags); 2 syncthreads/step (was 4)
//  - h staging via global_load_dwordx4 sc0 sc1 (agent-coherent, 8 instrs/thread)
//  - gates via v_exp/v_rcp (no libm tanh branches)

typedef unsigned short u16;
typedef unsigned long long u64;
typedef __bf16 bf16x8 __attribute__((ext_vector_type(8)));
typedef float f32x4 __attribute__((ext_vector_type(4)));

#define NCELL 4
#define HID 512
#define INP 1024
#define G4 2048
#define BATCH 32
#define SEQ 512
#define RLORA 8
#define NW 16   // workgroups per direction in recurrence
#define HPW 32  // HID / NW
#define HFRAG 16384  // u16 per dir per parity: [2 mt][16 ks][64 lane][8]

__device__ __forceinline__ float bf2f(u16 u) {
  union { uint32_t i; float f; } v;
  v.i = ((uint32_t)u) << 16;
  return v.f;
}
__device__ __forceinline__ u16 f2bf(float f) {
  union { float f; uint32_t i; } v;
  v.f = f;
  uint32_t lsb = (v.i >> 16) & 1;
  return (u16)((v.i + 0x7fffu + lsb) >> 16);
}
__device__ __forceinline__ float sig_fast(float x) {
  return __builtin_amdgcn_rcpf(1.f + __expf(-x));
}
__device__ __forceinline__ float tanh_fast(float x) {
  return 1.f - 2.f * __builtin_amdgcn_rcpf(1.f + __expf(2.f * x));
}

// ---------------- weight folding: W_eff = W + 2 * BL @ A  (fp32 in, bf16 out) ---------
template <int K>
__global__ void fold_kernel(const float* __restrict__ w, const float* __restrict__ a,
                            const float* __restrict__ bl, u16* __restrict__ weff) {
  int64_t idx = (int64_t)blockIdx.x * blockDim.x + threadIdx.x;
  if (idx >= (int64_t)NCELL * G4 * K) return;
  int d = (int)(idx % K);
  int64_t gc = idx / K;
  int cell = (int)(gc / G4);
  float acc = w[idx];
#pragma unroll
  for (int r = 0; r < RLORA; ++r)
    acc += 2.0f * bl[gc * RLORA + r] * a[(int64_t)cell * RLORA * K + r * K + d];
  weff[idx] = f2bf(acc);
}

__global__ void bias_kernel(const float* __restrict__ b_ih, const float* __restrict__ b_hh,
                            float* __restrict__ bias) {
  int i = blockIdx.x * blockDim.x + threadIdx.x;
  if (i < NCELL * G4) bias[i] = b_ih[i] + b_hh[i];
}

// ---------------- gx chunk GEMM (epilogue writes rec-packed layout) ----------------
// A: [B*SEQ][INP] (fp32 if AF32 else bf16); W: [dir][G4][INP] bf16
// gx: u16 [(dir*NW+wg)*CL + lcol][256 tid][16]  (pack idx = mt*8 + jl*4 + rr)
template <bool AF32>
__global__ __launch_bounds__(256) void gemm_kernel(const void* __restrict__ Ain,
                                                   const u16* __restrict__ W,
                                                   const float* __restrict__ bias,
                                                   u16* __restrict__ gx, int tw0, int tw1,
                                                   int CL, int lcl2) {
  __shared__ alignas(16) u16 As[128][72];
  __shared__ alignas(16) u16 Bs[128][72];
  const int tid = threadIdx.x;
  const int dir = blockIdx.z;
  const int m0 = blockIdx.x * 128;
  const int n0 = blockIdx.y * 128;
  const int tw = dir ? tw1 : tw0;
  const u16* Wc = W + (int64_t)dir * G4 * INP;
  const float* bc = bias + dir * G4;
  u16* gxd = gx + (int64_t)dir * NW * CL * 4096;
  const int wave = tid >> 6, lane = tid & 63;
  const int wm = wave & 1, wn = wave >> 1;
  const int llo = lane & 15, lhi = lane >> 4;

  int64_t aoff[4];
  const u16* bptr[4];
  int srow[4], ssc[4];
#pragma unroll
  for (int i = 0; i < 4; ++i) {
    int s = i * 256 + tid;
    srow[i] = s >> 3;
    ssc[i] = s & 7;
    int lr = m0 + srow[i];
    int b = lr >> lcl2;
    int tt = tw + (lr - (b << lcl2));
    aoff[i] = ((int64_t)b * SEQ + tt) * INP + ssc[i] * 8;
    bptr[i] = Wc + (int64_t)(n0 + srow[i]) * INP + ssc[i] * 8;
  }

  const f32x4 fzero = {0.f, 0.f, 0.f, 0.f};
  f32x4 acc[4][4];
#pragma unroll
  for (int i = 0; i < 4; ++i)
#pragma unroll
    for (int j = 0; j < 4; ++j) acc[i][j] = fzero;

  for (int kt = 0; kt < INP / 64; ++kt) {
    const int kb = kt * 64;
    __syncthreads();
#pragma unroll
    for (int i = 0; i < 4; ++i) {
      if (AF32) {
        const float* src = (const float*)Ain + aoff[i] + kb;
        uint32_t p[4];
#pragma unroll
        for (int q = 0; q < 4; ++q)
          p[q] = (uint32_t)f2bf(src[2 * q]) | ((uint32_t)f2bf(src[2 * q + 1]) << 16);
        *(uint4*)&As[srow[i]][ssc[i] * 8] = make_uint4(p[0], p[1], p[2], p[3]);
      } else {
        *(uint4*)&As[srow[i]][ssc[i] * 8] = *(const uint4*)((const u16*)Ain + aoff[i] + kb);
      }
      *(uint4*)&Bs[srow[i]][ssc[i] * 8] = *(const uint4*)(bptr[i] + kb);
    }
    __syncthreads();
#pragma unroll
    for (int ks = 0; ks < 2; ++ks) {
      bf16x8 af[4], bfr[4];
#pragma unroll
      for (int i = 0; i < 4; ++i) {
        af[i] = *(const bf16x8*)&As[wm * 64 + i * 16 + llo][ks * 32 + lhi * 8];
        bfr[i] = *(const bf16x8*)&Bs[wn * 64 + i * 16 + llo][ks * 32 + lhi * 8];
      }
#pragma unroll
      for (int i = 0; i < 4; ++i)
#pragma unroll
        for (int j = 0; j < 4; ++j)
          acc[i][j] = __builtin_amdgcn_mfma_f32_16x16x32_bf16(af[i], bfr[j], acc[i][j], 0, 0, 0);
    }
  }
  // epilogue: scatter into rec-packed layout
#pragma unroll
  for (int i = 0; i < 4; ++i) {
    const int lr0 = m0 + wm * 64 + i * 16 + lhi * 4;
    const int b = lr0 >> lcl2;              // same b for r=0..3 (lr0 % 4 == 0, CL >= 8)
    const int lcol0 = lr0 - (b << lcl2);
    const int mt = b >> 4, lh2 = (b >> 2) & 3, rr = b & 3;
#pragma unroll
    for (int j = 0; j < 4; ++j) {
      const int ncol = n0 + wn * 64 + j * 16 + llo;
      const int w = ncol >> 9, wgi = (ncol >> 5) & 15, jl = (ncol >> 4) & 1, lc = ncol & 15;
      const float bv = bc[ncol];
      const int rtid = w * 64 + lh2 * 16 + lc;
      u16* base = gxd + ((int64_t)wgi * CL + lcol0) * 4096 + rtid * 16 + mt * 8 + jl * 4 + rr;
#pragma unroll
      for (int r = 0; r < 4; ++r) base[(int64_t)r * 4096] = f2bf(acc[i][j][r] + bv);
    }
  }
}

// ---------------- recurrence chunk ----------------
template <bool OUTF32>
__global__ __launch_bounds__(256, 1) void rec_kernel(
    const u16* __restrict__ gx,    // packed [(dir*NW+wg)*CL + lcol][256][16]
    const u16* __restrict__ Whh,   // [2][G4][HID] bf16
    u16* __restrict__ hbuf,        // [2 dirs][2 par][HFRAG] u16, fragment order
    uint32_t* __restrict__ flags,  // [2 dirs][64 * 4] (16B stride per wave-flag)
    void* __restrict__ outp,
    float* __restrict__ hn, float* __restrict__ cn,  // fp32, in d_out
    float* __restrict__ cstate,    // [4 cells][B][H] fp32 (ws)
    int cell_base, int s0, int CL) {
  const int tid = threadIdx.x;
  const int dir = blockIdx.x / NW;
  const int wg = blockIdx.x % NW;
  const int hb = wg * HPW;
  const int wave = tid >> 6, lane = tid & 63;
  const int llo = lane & 15, lhi = lane >> 4;

  const u16* gxs = gx + ((int64_t)(dir * NW + wg) * CL) * 4096 + tid * 16;
  const u16* Wc = Whh + (int64_t)dir * G4 * HID;
  u16* hb_dir = hbuf + dir * (2 * HFRAG);
  uint32_t* flg = flags + dir * (64 * 4);
  float* cst = cstate + (int64_t)(cell_base + dir) * BATCH * HID;

  __shared__ alignas(16) u16 h_lds[2 * 16 * 64 * 8];  // fragment order, 32KB
  __shared__ float g_lds[4][BATCH][HPW + 1];

  // W_hh fragments for this wave's gate.
  uint4 wfrag[2][16];
#pragma unroll
  for (int j = 0; j < 2; ++j)
#pragma unroll
    for (int ks = 0; ks < 16; ++ks) {
      const int col = wave * HID + hb + j * 16 + llo;
      wfrag[j][ks] = *(const uint4*)(Wc + (int64_t)col * HID + ks * 32 + lhi * 8);
    }
  if (s0 == 0) {
    for (int i = tid; i < 2 * 16 * 64 * 8 / 2; i += 256) ((uint32_t*)h_lds)[i] = 0;
  }
  __syncthreads();
  // c state in registers (thread-private ownership of (cb, hb+j0..j0+3))
  const int cb = tid >> 3, j0 = (tid & 7) * 4;
  float creg[4];
#pragma unroll
  for (int u = 0; u < 4; ++u) creg[u] = (s0 == 0) ? 0.f : cst[cb * HID + hb + j0 + u];
  // writer's fragment address (ks = wg)
  const int wmt = cb >> 4, wllo = cb & 15, wlhi2 = j0 >> 3, wjof = j0 & 7;
  const int64_t wfragidx = ((int64_t)((wmt * 16 + wg) * 64 + wlhi2 * 16 + wllo) * 8 + wjof) >> 2;

  for (int s = s0; s < s0 + CL; ++s) {
    const int ls = s - s0;
    const int t = dir ? (SEQ - 1 - s) : s;
    const int lcol = dir ? (CL - 1 - ls) : ls;
    // gx pack prefetch (2 x b128)
    const uint4 g0 = *(const uint4*)(gxs + (int64_t)lcol * 4096);
    const uint4 g1 = *(const uint4*)(gxs + (int64_t)lcol * 4096 + 8);
    if (s > 0) {
      // all waves poll all 64 wave-flags (lane l -> flag l)
      uint32_t f;
      do {
        f = __hip_atomic_load(flg + lane * 4, __ATOMIC_RELAXED, __HIP_MEMORY_SCOPE_AGENT);
      } while (__any(f < (uint32_t)s));
      asm volatile("" ::: "memory");
      // stage this wave's 8KB quarter of h_{s-1}: 8 x b128 agent-coherent loads
      const u16* src = hb_dir + ((s - 1) & 1) * HFRAG + wave * 4096 + lane * 8;
      u16* dstl = h_lds + wave * 4096 + lane * 8;
      uint4 sv[8];
#pragma unroll
      for (int k = 0; k < 8; ++k)
        asm volatile("global_load_dwordx4 %0, %1, off sc0 sc1"
                     : "=v"(sv[k])
                     : "v"(src + k * 512)
                     : "memory");
      asm volatile("s_waitcnt vmcnt(0)" ::: "memory");
#pragma unroll
      for (int k = 0; k < 8; ++k) *(uint4*)(dstl + k * 512) = sv[k];
    }
    __syncthreads();
    // unpack gx -> acc
    f32x4 acc[2][2];
    acc[0][0][0] = bf2f((u16)(g0.x & 0xffff));
    acc[0][0][1] = bf2f((u16)(g0.x >> 16));
    acc[0][0][2] = bf2f((u16)(g0.y & 0xffff));
    acc[0][0][3] = bf2f((u16)(g0.y >> 16));
    acc[0][1][0] = bf2f((u16)(g0.z & 0xffff));
    acc[0][1][1] = bf2f((u16)(g0.z >> 16));
    acc[0][1][2] = bf2f((u16)(g0.w & 0xffff));
    acc[0][1][3] = bf2f((u16)(g0.w >> 16));
    acc[1][0][0] = bf2f((u16)(g1.x & 0xffff));
    acc[1][0][1] = bf2f((u16)(g1.x >> 16));
    acc[1][0][2] = bf2f((u16)(g1.y & 0xffff));
    acc[1][0][3] = bf2f((u16)(g1.y >> 16));
    acc[1][1][0] = bf2f((u16)(g1.z & 0xffff));
    acc[1][1][1] = bf2f((u16)(g1.z >> 16));
    acc[1][1][2] = bf2f((u16)(g1.w & 0xffff));
    acc[1][1][3] = bf2f((u16)(g1.w >> 16));
#pragma unroll
    for (int ks = 0; ks < 16; ++ks) {
      bf16x8 af[2];
#pragma unroll
      for (int mt = 0; mt < 2; ++mt)
        af[mt] = *(const bf16x8*)&h_lds[((mt * 16 + ks) * 64 + lane) * 8];
#pragma unroll
      for (int mt = 0; mt < 2; ++mt)
#pragma unroll
        for (int j = 0; j < 2; ++j)
          acc[mt][j] = __builtin_amdgcn_mfma_f32_16x16x32_bf16(
              af[mt], __builtin_bit_cast(bf16x8, wfrag[j][ks]), acc[mt][j], 0, 0, 0);
    }
    // cross-wave gate exchange
#pragma unroll
    for (int mt = 0; mt < 2; ++mt)
#pragma unroll
      for (int j = 0; j < 2; ++j)
#pragma unroll
        for (int r = 0; r < 4; ++r)
          g_lds[wave][mt * 16 + lhi * 4 + r][j * 16 + llo] = acc[mt][j][r];
    __syncthreads();
    float hv[4], cv[4];
    u16 h16[4];
#pragma unroll
    for (int u = 0; u < 4; ++u) {
      const int jj = j0 + u;
      const float gi = g_lds[0][cb][jj], gf = g_lds[1][cb][jj];
      const float gg = g_lds[2][cb][jj], go = g_lds[3][cb][jj];
      float c = creg[u];
      c = sig_fast(gf) * c + sig_fast(gi) * tanh_fast(gg);
      hv[u] = sig_fast(go) * tanh_fast(c);
      cv[u] = c;
      creg[u] = c;
      h16[u] = f2bf(hv[u]);
    }
    {
      const u64 hp = (u64)h16[0] | ((u64)h16[1] << 16) | ((u64)h16[2] << 32) | ((u64)h16[3] << 48);
      u64* hw = (u64*)(hb_dir + (s & 1) * HFRAG) + wfragidx;
      __hip_atomic_store(hw, hp, __ATOMIC_RELAXED, __HIP_MEMORY_SCOPE_AGENT);
    }
    // per-wave flag: RELEASE store drains this wave's h store (vmcnt) before posting
    if (lane == 0)
      __hip_atomic_store(flg + (wg * 4 + wave) * 4, (uint32_t)(s + 1), __ATOMIC_RELEASE,
                         __HIP_MEMORY_SCOPE_AGENT);
    // non-critical stores after the flag
    {
      const int64_t obase = ((int64_t)cb * SEQ + t) * (2 * HID) + dir * HID + hb + j0;
      if (OUTF32) {
        *(float4*)((float*)outp + obase) = make_float4(hv[0], hv[1], hv[2], hv[3]);
      } else {
        uint32_t* ow = (uint32_t*)((u16*)outp + obase);
        ow[0] = (uint32_t)h16[0] | ((uint32_t)h16[1] << 16);
        ow[1] = (uint32_t)h16[2] | ((uint32_t)h16[3] << 16);
      }
      if (s == SEQ - 1) {
        const int cg = cell_base + dir;
        const int64_t nbase = ((int64_t)cg * BATCH + cb) * HID + hb + j0;
        *(float4*)(hn + nbase) = make_float4(hv[0], hv[1], hv[2], hv[3]);
        *(float4*)(cn + nbase) = make_float4(cv[0], cv[1], cv[2], cv[3]);
      }
    }
  }
  // persist c for next chunk
#pragma unroll
  for (int u = 0; u < 4; ++u) cst[cb * HID + hb + j0 + u] = creg[u];
}

extern "C" void kernel_launch(void* const* d_in, const int* in_sizes, int n_in, void* d_out,
                              int out_size, void* d_ws, size_t ws_size, hipStream_t stream) {
  const float* x = (const float*)d_in[0];
  const float* w_ih = (const float*)d_in[1];
  const float* w_hh = (const float*)d_in[2];
  const float* b_ih = (const float*)d_in[3];
  const float* b_hh = (const float*)d_in[4];
  const float* a_ih = (const float*)d_in[5];
  const float* bl_ih = (const float*)d_in[6];
  const float* a_hh = (const float*)d_in[7];
  const float* bl_hh = (const float*)d_in[8];
  float* out = (float*)d_out;  // fp32 outputs

  char* ws = (char*)d_ws;
  const size_t O_WIH = 0;                                              // 16,777,216
  const size_t O_WHH = O_WIH + (size_t)NCELL * G4 * INP * 2;           // + 8,388,608
  const size_t O_BIAS = O_WHH + (size_t)NCELL * G4 * HID * 2;          // + 32,768
  const size_t O_CST = O_BIAS + (size_t)NCELL * G4 * 4;                // + 262,144
  const size_t O_HBUF = O_CST + (size_t)NCELL * BATCH * HID * 4;       // + 262,144
  const size_t O_FLAG = O_HBUF + (size_t)NCELL * 2 * BATCH * HID * 2;  // + 8,192
  const size_t O_MID = O_FLAG + 8192;                                  // + 33,554,432
  const size_t O_GX = O_MID + (size_t)BATCH * SEQ * 2 * HID * 2;       // + gx (bf16)
  u16* w_ih_eff = (u16*)(ws + O_WIH);
  u16* w_hh_eff = (u16*)(ws + O_WHH);
  float* bias = (float*)(ws + O_BIAS);
  float* cstate = (float*)(ws + O_CST);
  u16* hbuf = (u16*)(ws + O_HBUF);
  uint32_t* flags = (uint32_t*)(ws + O_FLAG);
  u16* mid = (u16*)(ws + O_MID);
  u16* gxb = (u16*)(ws + O_GX);

  int CL = 128;
  while (CL > 8 && O_GX + (size_t)2 * NW * CL * 4096 * 2 > ws_size) CL >>= 1;
  const int lcl2 = __builtin_ctz(CL);
  const int nch = SEQ / CL;

  (void)hipMemsetAsync(ws + O_FLAG, 0, 8192, stream);

  {
    int64_t tot = (int64_t)NCELL * G4 * INP;
    fold_kernel<INP><<<(int)((tot + 255) / 256), 256, 0, stream>>>(w_ih, a_ih, bl_ih, w_ih_eff);
  }
  {
    int64_t tot = (int64_t)NCELL * G4 * HID;
    fold_kernel<HID><<<(int)((tot + 255) / 256), 256, 0, stream>>>(w_hh, a_hh, bl_hh, w_hh_eff);
  }
  bias_kernel<<<(NCELL * G4 + 255) / 256, 256, 0, stream>>>(b_ih, b_hh, bias);

  float* hn = out + (size_t)BATCH * SEQ * (2 * HID);
  float* cn = hn + (size_t)NCELL * BATCH * HID;

  dim3 gemm_grid(BATCH * CL / 128, G4 / 128, 2);
  for (int layer = 0; layer < 2; ++layer) {
    const u16* wih = w_ih_eff + (size_t)layer * 2 * G4 * INP;
    const u16* whh = w_hh_eff + (size_t)layer * 2 * G4 * HID;
    const float* bi = bias + (size_t)layer * 2 * G4;
    u16* hb = hbuf + (size_t)layer * 2 * (2 * HFRAG);
    uint32_t* fl = flags + (size_t)layer * 2 * (64 * 4);
    for (int ci = 0; ci < nch; ++ci) {
      const int tw0 = ci * CL;
      const int tw1 = SEQ - (ci + 1) * CL;
      if (layer == 0) {
        gemm_kernel<true><<<gemm_grid, 256, 0, stream>>>(x, wih, bi, gxb, tw0, tw1, CL, lcl2);
        rec_kernel<false><<<2 * NW, 256, 0, stream>>>(gxb, whh, hb, fl, mid, hn, cn, cstate,
                                                      0, ci * CL, CL);
      } else {
        gemm_kernel<false><<<gemm_grid, 256, 0, stream>>>(mid, wih, bi, gxb, tw0, tw1, CL, lcl2);
        rec_kernel<true><<<2 * NW, 256, 0, stream>>>(gxb, whh, hb, fl, out, hn, cn, cstate,
                                                     2, ci * CL, CL);
      }
    }
  }
}